// Round 5
// baseline (18738.562 us; speedup 1.0000x reference)
//
#include <hip/hip_runtime.h>
#include <hip/hip_bf16.h>
#include <stdint.h>
#include <stddef.h>

// Problem constants
#define B_ 4096
#define S_ 64
#define D_ 512
#define DEPTH_ 4

// ---------------------------------------------------------------------------
// R15 design = R14 (best known, 14751us) + one structural delta:
//  * fused_layer: ONE kernel per layer replacing [addln/lnfold smallgemm +
//    ln_sum1]: TM=16 FULL-WIDTH rows (TN=512), grid B/16=256 blocks.
//    prologue: fold X+PSPL ONCE (was x4 col-dup), x kept in regs (vx),
//    LN1 -> swizzled sY. Barrier-free K-loop (R14): A=sY LDS, B=whole Wc
//    direct L2. Epilogue: acc+bc -> sP (f32 LDS), x = vx + P1 (f32, one
//    fewer bf16 rounding), X written in place, LN2 -> Y.
//    Kills per layer: 1 dispatch+gap, P1 4MB round-trip, 3/4 of fold-read
//    duplication; X ping-pong gone (blocks own full rows).
//    Risk noted: 256-block grid (1 block/CU) — prior 256-block regressions
//    were on barrier-heavy staged GEMMs; this kernel has 2 barriers.
//  * Big GEMMs g2/g3 untouched (TM=128 locked, R12 anti-lesson).
//  * Locked per R10-R14: m97 2-barrier K-loop for big GEMMs, BK=64,
//    global_load_lds width=16, coalesced LDS-staged epilogues, split-K=4
//    g3 with plain bf16 partials, no cross-block sync, no XCD swizzle.
// ---------------------------------------------------------------------------

typedef __attribute__((ext_vector_type(8))) __bf16 bf16x8;
typedef __attribute__((ext_vector_type(4))) float f32x4;
typedef __hip_bfloat16 bf16_t;

constexpr int SPLITZ = 4;   // g3 split-K partials

__device__ __forceinline__ void async_copy16(const void* g, void* lds) {
  __builtin_amdgcn_global_load_lds(
      (const __attribute__((address_space(1))) void*)g,
      (__attribute__((address_space(3))) void*)lds, 16, 0, 0);
}

__device__ __forceinline__ float bf2f(bf16_t h) { return __bfloat162float(h); }

// fold bf16 partial row-chunk into v[8]
__device__ __forceinline__ void fold_p(float v[8], const bf16_t* pz)
{
  alignas(16) bf16_t t[8];
  *(uint4*)t = *(const uint4*)pz;
#pragma unroll
  for (int i = 0; i < 8; ++i) v[i] += bf2f(t[i]);
}

// LayerNorm row math shared by the storers
__device__ __forceinline__ void ln_vals(const float v[8],
                                        const float* __restrict__ gamma,
                                        const float* __restrict__ beta,
                                        int lane, bf16_t o8[8])
{
  float s = 0.f, ss = 0.f;
#pragma unroll
  for (int i = 0; i < 8; ++i) { s += v[i]; ss += v[i] * v[i]; }
#pragma unroll
  for (int o = 32; o; o >>= 1) { s += __shfl_xor(s, o); ss += __shfl_xor(ss, o); }
  const float m   = s * (1.f / D_);
  const float inv = rsqrtf(ss * (1.f / D_) - m * m + 1e-5f);
  const int c0 = lane * 8;
  float g[8], b[8];
  *(float4*)&g[0] = *(const float4*)&gamma[c0];
  *(float4*)&g[4] = *(const float4*)&gamma[c0 + 4];
  *(float4*)&b[0] = *(const float4*)&beta[c0];
  *(float4*)&b[4] = *(const float4*)&beta[c0 + 4];
#pragma unroll
  for (int i = 0; i < 8; ++i)
    o8[i] = __float2bfloat16((v[i] - m) * inv * g[i] + b[i]);
}

// LN + plain row store (global Y rows)
__device__ __forceinline__ void ln_store(const float v[8],
                                         const float* __restrict__ gamma,
                                         const float* __restrict__ beta,
                                         bf16_t* yrow, int lane)
{
  alignas(16) bf16_t o8[8];
  ln_vals(v, gamma, beta, lane, o8);
  *(uint4*)&yrow[lane * 8] = *(const uint4*)o8;
}

// LN + XOR-swizzled LDS row store: elem ^= (row&7)<<3 (bank-spread for the
// stride-1024B ds_read_b128 in the K-loop; bijective within the row)
__device__ __forceinline__ void ln_store_swz(const float v[8],
                                             const float* __restrict__ gamma,
                                             const float* __restrict__ beta,
                                             bf16_t* srow, int row, int lane)
{
  alignas(16) bf16_t o8[8];
  ln_vals(v, gamma, beta, lane, o8);
  const int c0s = (lane * 8) ^ ((row & 7) << 3);
  *(uint4*)&srow[c0s] = *(const uint4*)o8;
}

// ---------------------------------------------------------------------------
// GEMM: C(M,N) = A(M,K) @ Bt(N,K)^T  (+bias)
//   EPI 1: O[row*N+col]  = bf16(relu(acc+b))   (SPLITK==1)
//   EPI 2: O[z*M*N + row*N+col] = bf16(acc (+bias if z==0))
// ---------------------------------------------------------------------------
template<int TM, int TN, int EPI, int SPLITK>
__launch_bounds__(256)
__global__ void gemm_bf16(const bf16_t* __restrict__ A,
                          const bf16_t* __restrict__ Bt,
                          const float* __restrict__ bias,
                          bf16_t* __restrict__ O,
                          int M, int N, int K)
{
  constexpr int BK  = 64;
  constexpr int WM  = TM / 2, WN = TN / 2;
  constexpr int NMI = WM / 16, NNI = WN / 16;
  constexpr int CA  = TM / 8, CB = TN / 8;   // 1KB chunks (8 rows of 128B)
  static_assert(TM * TN <= (TM + TN) * BK, "C tile must fit in staging LDS");

  __shared__ __align__(16) bf16_t smem[(TM + TN) * BK];
  bf16_t* sA = smem;
  bf16_t* sB = smem + TM * BK;

  const int tid  = threadIdx.x;
  const int lane = tid & 63;
  const int wave = tid >> 6;
  const int wm   = wave & 1;
  const int wn   = wave >> 1;
  const int m0   = blockIdx.x * TM;
  const int n0   = blockIdx.y * TN;
  const int KS   = K / SPLITK;
  const int kbeg = blockIdx.z * KS;

  const int lr = lane >> 3;        // row within 1KB chunk (8 rows)
  const int lc = (lane & 7) * 8;   // bf16 col within row

  f32x4 acc[NMI][NNI];
#pragma unroll
  for (int mi = 0; mi < NMI; ++mi)
#pragma unroll
    for (int ni = 0; ni < NNI; ++ni)
      acc[mi][ni] = (f32x4){0.f, 0.f, 0.f, 0.f};

  for (int k0 = kbeg; k0 < kbeg + KS; k0 += BK) {
#pragma unroll
    for (int c = wave; c < CA; c += 4) {
      const bf16_t* g = A + (size_t)(m0 + c * 8 + lr) * K + (k0 + lc);
      async_copy16(g, (char*)sA + c * 1024);
    }
#pragma unroll
    for (int c = wave; c < CB; c += 4) {
      const bf16_t* g = Bt + (size_t)(n0 + c * 8 + lr) * K + (k0 + lc);
      async_copy16(g, (char*)sB + c * 1024);
    }
    __syncthreads();   // drains vmcnt(0) -> LDS ready

#pragma unroll
    for (int kk = 0; kk < BK; kk += 32) {
      bf16x8 af[NMI], bfv[NNI];
#pragma unroll
      for (int mi = 0; mi < NMI; ++mi)
        af[mi] = *(const bf16x8*)&sA[(wm * WM + mi * 16 + (lane & 15)) * BK + kk + (lane >> 4) * 8];
#pragma unroll
      for (int ni = 0; ni < NNI; ++ni)
        bfv[ni] = *(const bf16x8*)&sB[(wn * WN + ni * 16 + (lane & 15)) * BK + kk + (lane >> 4) * 8];
#pragma unroll
      for (int mi = 0; mi < NMI; ++mi)
#pragma unroll
        for (int ni = 0; ni < NNI; ++ni)
          acc[mi][ni] = __builtin_amdgcn_mfma_f32_16x16x32_bf16(af[mi], bfv[ni], acc[mi][ni], 0, 0, 0);
    }
    __syncthreads();   // protect LDS before next stage / before sC reuse
  }

  // Coalesced epilogue: round into LDS (reuse staging buffer), then
  // row-major uint4 stores. C/D layout (m89/m91): col=lane&15,
  // row=(lane>>4)*4 + r.
  bf16_t* sC = smem;
#pragma unroll
  for (int mi = 0; mi < NMI; ++mi) {
#pragma unroll
    for (int ni = 0; ni < NNI; ++ni) {
      const int col  = wn * WN + ni * 16 + (lane & 15);
      const int row0 = wm * WM + mi * 16 + ((lane >> 4) << 2);
      const float bv = (SPLITK == 1 || blockIdx.z == 0) ? bias[n0 + col] : 0.f;
#pragma unroll
      for (int r = 0; r < 4; ++r) {
        float v = acc[mi][ni][r] + bv;
        if constexpr (EPI == 1) v = v > 0.f ? v : 0.f;
        sC[(row0 + r) * TN + col] = __float2bfloat16(v);
      }
    }
  }
  __syncthreads();
  bf16_t* Ob = O + (EPI == 2 ? (size_t)blockIdx.z * M * N : (size_t)0);
#pragma unroll
  for (int p = 0; p < (TM * TN) / 2048; ++p) {
    const int chunk = p * 256 + tid;
    const int rr = chunk / (TN / 8);
    const int cc = (chunk % (TN / 8)) * 8;
    *(uint4*)&Ob[(size_t)(m0 + rr) * N + n0 + cc] = *(const uint4*)&sC[rr * TN + cc];
  }
}

// ---------------------------------------------------------------------------
// fused_layer<L0>: one kernel per layer =
//   [h/x fold (+emb/head if L0); LN1 -> sY] + [P1 = y@Wc + bc, full width]
//   + [x = vx + P1 (f32); write X in place; Y = LN2(x)]
// TM=16 rows, TN=512 (full width), grid B/16 = 256 blocks, 256 thr.
// LDS: sY 16KB (swizzled bf16 A-panel) + sP 33KB (padded f32 P1) = 49KB.
// Two barriers total. B read direct from L2-hot Wc (R14-validated).
// ---------------------------------------------------------------------------
template<bool L0>
__launch_bounds__(256)
__global__ void fused_layer(float* __restrict__ X,          // in-place
                            const bf16_t* __restrict__ P,   // PSPL or null
                            const float* __restrict__ g1,
                            const float* __restrict__ b1,
                            const bf16_t* __restrict__ Bt,  // WCT layer slice
                            const float* __restrict__ bias, // BC layer slice
                            const float* __restrict__ g2v,
                            const float* __restrict__ b2v,
                            bf16_t* __restrict__ Y,
                            // L0-only:
                            const int* __restrict__ a_seq,
                            const int* __restrict__ b_seq,
                            const float* __restrict__ bit_emb,
                            const float* __restrict__ hsrc, int hstride,
                            int t,
                            const float* __restrict__ hw,
                            const float* __restrict__ hb,
                            float* __restrict__ out)
{
  constexpr int TM  = 16;
  constexpr int SPS = D_ + 4;   // f32 pad: float4-aligned rows, 2-way banks
  __shared__ __align__(16) bf16_t sY[TM * D_];      // 16KB
  __shared__ __align__(16) float  sP[TM * SPS];     // 33KB

  const int tid  = threadIdx.x;
  const int lane = tid & 63;
  const int wave = tid >> 6;
  const int m0   = blockIdx.x * TM;
  const int c0   = lane * 8;

  float w[16];
  const bool do_head = L0 && (out != nullptr);
  if (do_head) {
#pragma unroll
    for (int i = 0; i < 4; ++i)
      *(float4*)&w[i * 4] = *(const float4*)&hw[lane * 16 + i * 4];
  }

  // ---- prologue: 4 rows per wave; x kept in vx; LN1 -> sY (swizzled) ----
  float vx[4][8];
#pragma unroll
  for (int i = 0; i < 4; ++i) {
    const int row  = wave * 4 + i;
    const int grow = m0 + row;
    float v[8];
    if constexpr (L0) {
      const float* pr = hsrc + (size_t)grow * hstride + c0;
      float p[8];
      *(float4*)&p[0] = *(const float4*)&pr[0];
      *(float4*)&p[4] = *(const float4*)&pr[4];
      if (P != nullptr) {
#pragma unroll
        for (int z = 0; z < SPLITZ; ++z)
          fold_p(p, P + (size_t)z * B_ * D_ + (size_t)grow * D_ + c0);
      }
      if (do_head) {
        float s0 = 0.f, s1 = 0.f;
#pragma unroll
        for (int j = 0; j < 8; ++j) { s0 += p[j] * w[2 * j]; s1 += p[j] * w[2 * j + 1]; }
#pragma unroll
        for (int o = 32; o; o >>= 1) { s0 += __shfl_xor(s0, o); s1 += __shfl_xor(s1, o); }
        if (lane == 0) {
          float* po = out + (size_t)grow * (S_ * 2) + (t - 1) * 2;
          po[0] = s0 + hb[0];
          po[1] = s1 + hb[1];
        }
      }
      const int ai = a_seq[grow * S_ + t];
      const int bi = b_seq[grow * S_ + t];
      float ea[8], eb[8];
      *(float4*)&ea[0] = *(const float4*)&bit_emb[ai * D_ + c0];
      *(float4*)&ea[4] = *(const float4*)&bit_emb[ai * D_ + c0 + 4];
      *(float4*)&eb[0] = *(const float4*)&bit_emb[bi * D_ + c0];
      *(float4*)&eb[4] = *(const float4*)&bit_emb[bi * D_ + c0 + 4];
#pragma unroll
      for (int j = 0; j < 8; ++j) v[j] = ea[j] + eb[j] + p[j];
    } else {
      const float* xr = X + (size_t)grow * D_ + c0;
      *(float4*)&v[0] = *(const float4*)&xr[0];
      *(float4*)&v[4] = *(const float4*)&xr[4];
#pragma unroll
      for (int z = 0; z < SPLITZ; ++z)
        fold_p(v, P + (size_t)z * B_ * D_ + (size_t)grow * D_ + c0);
    }
#pragma unroll
    for (int j = 0; j < 8; ++j) vx[i][j] = v[j];
    ln_store_swz(v, g1, b1, &sY[row * D_], row, lane);
  }
  __syncthreads();   // sY visible

  // ---- barrier-free K-loop: A = sY (16 rows), B = direct global Wc ----
  f32x4 acc[8];
#pragma unroll
  for (int ni = 0; ni < 8; ++ni) acc[ni] = (f32x4){0.f, 0.f, 0.f, 0.f};

  const bf16_t* bb = Bt + (size_t)(wave * 128 + (lane & 15)) * D_ + (lane >> 4) * 8;
  const int r0 = lane & 15;
  const int x0 = (r0 & 7) << 3;
  const int ka = (lane >> 4) * 8;
#pragma unroll
  for (int k0 = 0; k0 < D_; k0 += 32) {
    const bf16x8 af = *(const bf16x8*)&sY[r0 * D_ + ((k0 + ka) ^ x0)];
#pragma unroll
    for (int ni = 0; ni < 8; ++ni) {
      const bf16x8 bv = *(const bf16x8*)&bb[(size_t)ni * 16 * D_ + k0];
      acc[ni] = __builtin_amdgcn_mfma_f32_16x16x32_bf16(af, bv, acc[ni], 0, 0, 0);
    }
  }

  // ---- epilogue: acc(+bc) -> sP ; x = vx + P1 ; X write ; LN2 -> Y ----
  const int prow0 = (lane >> 4) << 2;
#pragma unroll
  for (int ni = 0; ni < 8; ++ni) {
    const int col = wave * 128 + ni * 16 + (lane & 15);
    const float bv = bias[col];
#pragma unroll
    for (int r = 0; r < 4; ++r)
      sP[(prow0 + r) * SPS + col] = acc[ni][r] + bv;
  }
  __syncthreads();   // sP complete

#pragma unroll
  for (int i = 0; i < 4; ++i) {
    const int row  = wave * 4 + i;
    const int grow = m0 + row;
    const float* pr = &sP[row * SPS + c0];
    float v[8];
    *(float4*)&v[0] = *(const float4*)&pr[0];
    *(float4*)&v[4] = *(const float4*)&pr[4];
#pragma unroll
    for (int j = 0; j < 8; ++j) v[j] += vx[i][j];
    float* xo = X + (size_t)grow * D_ + c0;
    *(float4*)&xo[0] = *(const float4*)&v[0];
    *(float4*)&xo[4] = *(const float4*)&v[4];
    ln_store(v, g2v, b2v, &Y[(size_t)grow * D_], lane);
  }
}

// Final head: h = X + P0..P3; logits[row, S-1, :] = h @ head_w + head_b.
__global__ void head_kernel(const float* __restrict__ X,
                            const bf16_t* __restrict__ P,
                            const float* __restrict__ hw,
                            const float* __restrict__ hb,
                            float* __restrict__ out, int t)
{
  const int row  = blockIdx.x * 4 + (threadIdx.x >> 6);
  const int lane = threadIdx.x & 63;
  const float* xr = X + (size_t)row * D_;
  const int c0 = lane * 8;
  float v[8];
  *(float4*)&v[0] = *(const float4*)&xr[c0];
  *(float4*)&v[4] = *(const float4*)&xr[c0 + 4];
#pragma unroll
  for (int z = 0; z < SPLITZ; ++z)
    fold_p(v, P + (size_t)z * B_ * D_ + (size_t)row * D_ + c0);
  float w[16];
#pragma unroll
  for (int i = 0; i < 4; ++i)
    *(float4*)&w[i * 4] = *(const float4*)&hw[lane * 16 + i * 4];
  float s0 = 0.f, s1 = 0.f;
#pragma unroll
  for (int i = 0; i < 8; ++i) { s0 += v[i] * w[2 * i]; s1 += v[i] * w[2 * i + 1]; }
#pragma unroll
  for (int o = 32; o; o >>= 1) { s0 += __shfl_xor(s0, o); s1 += __shfl_xor(s1, o); }
  if (lane == 0) {
    float* po = out + (size_t)row * (S_ * 2) + t * 2;
    po[0] = s0 + hb[0];
    po[1] = s1 + hb[1];
  }
}

// ---------------------------------------------------------------------------
// Prep kernels (run every launch; graph-safe)
// ---------------------------------------------------------------------------
__global__ void prep_wc(const float* __restrict__ qkv_w,
                        const float* __restrict__ out_w,
                        float* __restrict__ wc)
{
  const int n = blockIdx.x * 256 + threadIdx.x;
  const int k = blockIdx.y;
  const int l = blockIdx.z;
  const float* qrow = qkv_w + ((size_t)l * D_ + k) * (3 * D_) + 2 * D_;
  const float* ow   = out_w + (size_t)l * D_ * D_;
  float acc = 0.f;
  for (int j = 0; j < D_; ++j) acc += qrow[j] * ow[(size_t)j * D_ + n];
  wc[((size_t)l * D_ + k) * D_ + n] = acc;
}

__global__ void prep_bc(const float* __restrict__ qkv_b,
                        const float* __restrict__ out_w,
                        const float* __restrict__ out_b,
                        float* __restrict__ bc)
{
  const int l = blockIdx.x;
  const int n = threadIdx.x;
  const float* qb = qkv_b + (size_t)l * (3 * D_) + 2 * D_;
  const float* ow = out_w + (size_t)l * D_ * D_;
  float acc = out_b[(size_t)l * D_ + n];
  for (int j = 0; j < D_; ++j) acc += qb[j] * ow[(size_t)j * D_ + n];
  bc[(size_t)l * D_ + n] = acc;
}

// dst(C,R) bf16 = transpose(src(R,C) fp32), per-layer via blockIdx.z
__global__ void transpose_conv(const float* __restrict__ src,
                               bf16_t* __restrict__ dst, int R, int C)
{
  __shared__ float tile[32][33];
  const int l = blockIdx.z;
  const float* s = src + (size_t)l * R * C;
  bf16_t* d = dst + (size_t)l * R * C;
  const int c0 = blockIdx.x * 32, r0 = blockIdx.y * 32;
  const int tx = threadIdx.x, ty = threadIdx.y;
  tile[ty][tx] = s[(size_t)(r0 + ty) * C + (c0 + tx)];
  __syncthreads();
  d[(size_t)(c0 + ty) * R + (r0 + tx)] = __float2bfloat16(tile[tx][ty]);
}

// ---------------------------------------------------------------------------
extern "C" void kernel_launch(void* const* d_in, const int* in_sizes, int n_in,
                              void* d_out, int out_size, void* d_ws, size_t ws_size,
                              hipStream_t stream)
{
  const int*   a_seq     = (const int*)  d_in[0];
  const int*   b_seq     = (const int*)  d_in[1];
  const float* bit_emb   = (const float*)d_in[2];
  const float* start     = (const float*)d_in[3];
  const float* ln1_g     = (const float*)d_in[4];
  const float* ln1_b     = (const float*)d_in[5];
  const float* qkv_w     = (const float*)d_in[6];
  const float* qkv_b     = (const float*)d_in[7];
  const float* out_w     = (const float*)d_in[8];
  const float* out_b     = (const float*)d_in[9];
  const float* ln2_g     = (const float*)d_in[10];
  const float* ln2_b     = (const float*)d_in[11];
  const float* ff1_w     = (const float*)d_in[12];
  const float* ff1_b     = (const float*)d_in[13];
  const float* ff2_w     = (const float*)d_in[14];
  const float* ff2_b     = (const float*)d_in[15];
  const float* head_w    = (const float*)d_in[16];
  const float* head_b    = (const float*)d_in[17];
  float* out = (float*)d_out;

  // workspace layout
  char* ws = (char*)d_ws;
  float*  X     = (float*) ws; ws += (size_t)B_ * D_ * 4;              // 8 MB (single buffer now)
  bf16_t* Y     = (bf16_t*)ws; ws += (size_t)B_ * D_ * 2;              // 4 MB
  bf16_t* U     = (bf16_t*)ws; ws += (size_t)B_ * 4 * D_ * 2;          // 16 MB
  bf16_t* WCT   = (bf16_t*)ws; ws += (size_t)DEPTH_ * D_ * D_ * 2;     // 2 MB
  bf16_t* FF1T  = (bf16_t*)ws; ws += (size_t)DEPTH_ * D_ * 4 * D_ * 2; // 8 MB
  bf16_t* FF2T  = (bf16_t*)ws; ws += (size_t)DEPTH_ * 4 * D_ * D_ * 2; // 8 MB
  float*  BC    = (float*) ws; ws += (size_t)DEPTH_ * D_ * 4;          // 8 KB
  float*  WCTMP = (float*) ws; ws += (size_t)DEPTH_ * D_ * D_ * 4;     // 4 MB
  bf16_t* PSPL  = (bf16_t*)ws; ws += (size_t)SPLITZ * B_ * D_ * 2;     // 16 MB g3 split-K partials

  // ---- weight prep (per launch, identical every call) ----
  prep_wc<<<dim3(2, 512, 4), 256, 0, stream>>>(qkv_w, out_w, WCTMP);
  prep_bc<<<4, 512, 0, stream>>>(qkv_b, out_w, out_b, BC);
  transpose_conv<<<dim3(16, 16, 4),  dim3(32, 32), 0, stream>>>(WCTMP, WCT, 512, 512);
  transpose_conv<<<dim3(64, 16, 4),  dim3(32, 32), 0, stream>>>(ff1_w, FF1T, 512, 2048);
  transpose_conv<<<dim3(16, 64, 4),  dim3(32, 32), 0, stream>>>(ff2_w, FF2T, 2048, 512);

  // ---- recurrent steps (12 dispatches/step) ----
  // Single X buffer, in-place: each fused_layer block owns its 16 full rows.
  for (int t = 0; t < S_; ++t) {
    for (int l = 0; l < DEPTH_; ++l) {
      if (l == 0) {
        if (t == 0)
          fused_layer<true><<<B_ / 16, 256, 0, stream>>>(
              X, nullptr, ln1_g, ln1_b, WCT, BC, ln2_g, ln2_b, Y,
              a_seq, b_seq, bit_emb, start, 0, t, head_w, head_b, nullptr);
        else
          fused_layer<true><<<B_ / 16, 256, 0, stream>>>(
              X, PSPL, ln1_g, ln1_b, WCT, BC, ln2_g, ln2_b, Y,
              a_seq, b_seq, bit_emb, X, D_, t, head_w, head_b, out);
      } else {
        fused_layer<false><<<B_ / 16, 256, 0, stream>>>(
            X, PSPL,
            ln1_g + (size_t)l * D_, ln1_b + (size_t)l * D_,
            WCT + (size_t)l * D_ * D_, BC + (size_t)l * D_,
            ln2_g + (size_t)l * D_, ln2_b + (size_t)l * D_, Y,
            nullptr, nullptr, nullptr, nullptr, 0, 0, nullptr, nullptr, nullptr);
      }
      // u = relu(y @ ff1[l] + b1)  (128x128, BK=64, 512 blocks)
      gemm_bf16<128, 128, 1, 1><<<dim3(32, 16), 256, 0, stream>>>(
          Y, FF1T + (size_t)l * D_ * 4 * D_, ff1_b + (size_t)l * 4 * D_, U,
          B_, 4 * D_, D_);
      // PSPL[z] = bf16(u @ ff2[l] (+b2 in z=0))  (128x128, split-K=4,
      //           grid (32,4,4)=512 blocks, 8 BK-iters/block)
      gemm_bf16<128, 128, 2, SPLITZ><<<dim3(32, 4, SPLITZ), 256, 0, stream>>>(
          U, FF2T + (size_t)l * 4 * D_ * D_, ff2_b + (size_t)l * D_, PSPL,
          B_, D_, 4 * D_);
      // PSPL folded by next fused_layer / head
    }
  }
  head_kernel<<<B_ / 4, 256, 0, stream>>>(X, PSPL, head_w, head_b, out, S_ - 1);
}